// Round 4
// baseline (552.328 us; speedup 1.0000x reference)
//
#include <hip/hip_runtime.h>

// GP_36206574305645: out[b,d,n] = sum_m softmax_m(sim[b,n,m]) * f[m,d]
//   b=4, hw=4096 (h=w=64), d=64. sim fp32 268 MB read-once.
// Overhead per iter: 1 GiB ws-poison fill ~160us + input restore ~81us.
// R3 371 / R4 376 / R6 387.5: three structurally different kernels
//   (ft traffic 134/268/~64 MB, occupancy 8/16/16 waves per CU, reg vs LDS
//   staging) all land within noise => ft traffic, occupancy, and reg-prefetch
//   depth are ALL falsified as the bottleneck. Remaining hypotheses:
//   H-pattern (16KB-strided multi-stream sim reads cap at ~2.5-3 TB/s) vs
//   H-fine (pattern streams ~6 TB/s; time lost inside gp_part: spills/stalls).
// R7 (MEASUREMENT ROUND): R6 chain kept byte-identical + 3x sim_probe
//   (replays gp_part's exact sim address stream, load+accumulate only,
//   result dumped to dead ws at +32MB). dur - 387.5 = 3 * t_probe.
//   Pre-committed: ~510-540 => H-fine (fix gp_part internals next);
//   ~660-760 => H-pattern (two-pass exp-transpose restructure next).

typedef _Float16 f16;
typedef f16 f16x8 __attribute__((ext_vector_type(8)));
typedef float f32x4 __attribute__((ext_vector_type(4)));

static constexpr int HW  = 4096;     // h*w
static constexpr int ND  = 64;       // gp_dim
static constexpr int MS  = 4;        // m-split (slices)
static constexpr int MSL = HW / MS;  // 1024 m per slice
static constexpr int CH  = 128;      // staged chunk (m)
static constexpr int NCH = MSL / CH; // 8 chunks

// ---------------------------------------------------------------- kernel A --
__global__ __launch_bounds__(256) void posenc_f16(
    const float* __restrict__ cw, const float* __restrict__ cb,
    f16* __restrict__ ft)
{
    int g = blockIdx.x * 256 + threadIdx.x;      // 0 .. 64*4096-1
    int d = g >> 12;
    int m = g & 4095;
    int i = m >> 6;
    int j = m & 63;
    float gx = (float)(2 * j - 63) * (1.0f / 64.0f);
    float gy = (float)(2 * i - 63) * (1.0f / 64.0f);
    float proj = cw[2 * d] * gx + cw[2 * d + 1] * gy + cb[d];
    float v = cosf(25.132741228718345f * proj);  // 8*pi
    ft[(size_t)d * HW + m] = (f16)v;
}

// ---------------------------------------------------------------- kernel B --
// (identical to R6 — known-passing, known 387.5us total)
__device__ __forceinline__ void chunk_compute(
    const f32x4* sA, const f16* __restrict__ fb,
    int c, int q, int c7, f32x4 acc[4], float& ps)
{
    #pragma unroll
    for (int st = 0; st < 4; st++) {
        const f16* fbb = fb + c * CH + (((st * 4 + q) ^ c7) * 8);
        f16x8 b0 = *(const f16x8*)(fbb);
        f16x8 b1 = *(const f16x8*)(fbb + 16 * CH);
        f16x8 b2 = *(const f16x8*)(fbb + 32 * CH);
        f16x8 b3 = *(const f16x8*)(fbb + 48 * CH);

        f32x4 s0 = sA[2 * st];
        f32x4 s1 = sA[2 * st + 1];
        float p0 = __expf(s0[0]); float p1 = __expf(s0[1]);
        float p2 = __expf(s0[2]); float p3 = __expf(s0[3]);
        float p4 = __expf(s1[0]); float p5 = __expf(s1[1]);
        float p6 = __expf(s1[2]); float p7 = __expf(s1[3]);
        ps += ((p0 + p1) + (p2 + p3)) + ((p4 + p5) + (p6 + p7));
        f16x8 a;
        a[0] = (f16)p0; a[1] = (f16)p1; a[2] = (f16)p2; a[3] = (f16)p3;
        a[4] = (f16)p4; a[5] = (f16)p5; a[6] = (f16)p6; a[7] = (f16)p7;

        acc[0] = __builtin_amdgcn_mfma_f32_16x16x32_f16(a, b0, acc[0], 0, 0, 0);
        acc[1] = __builtin_amdgcn_mfma_f32_16x16x32_f16(a, b1, acc[1], 0, 0, 0);
        acc[2] = __builtin_amdgcn_mfma_f32_16x16x32_f16(a, b2, acc[2], 0, 0, 0);
        acc[3] = __builtin_amdgcn_mfma_f32_16x16x32_f16(a, b3, acc[3], 0, 0, 0);
    }
}

#define NTLOAD(p) __builtin_nontemporal_load((const f32x4*)(p))

__global__ __launch_bounds__(512, 4) void gp_part(
    const float* __restrict__ sim, const f16* __restrict__ ft,
    float* __restrict__ P, float* __restrict__ S)
{
    const int bb   = blockIdx.x >> 7;          // batch
    const int ms   = (blockIdx.x >> 5) & 3;    // m-slice
    const int ng   = blockIdx.x & 31;          // 128-row n-group
    const int tid  = threadIdx.x;
    const int wv   = tid >> 6;
    const int lane = tid & 63;
    const int c    = lane & 15;
    const int q    = lane >> 4;
    const int c7   = c & 7;

    __shared__ f16 ftile[2][64 * CH];          // 2 x 16 KB

    const int mb = ms * MSL;
    const int nr = ng * 128 + wv * 16;

    const float* sb = sim + (size_t)bb * HW * HW + (size_t)(nr + c) * HW
                          + mb + q * 8;

    const int d0 = tid >> 4;
    const int sl = tid & 15;
    const f16* fsrc = ft + (size_t)d0 * HW + mb + sl * 8;
    const int  fdo  = d0 * CH + ((sl ^ (d0 & 7)) * 8);   // swizzled f16 offset

    f32x4 acc[4];
    #pragma unroll
    for (int u = 0; u < 4; u++)
        acc[u] = (f32x4){0.f, 0.f, 0.f, 0.f};
    float ps = 0.f;

    f32x4 sA[8], sB[8];
    f16x8 gA0, gA1, gB0, gB1;

    gA0 = *(const f16x8*)(fsrc);
    gA1 = *(const f16x8*)(fsrc + (size_t)32 * HW);
    #pragma unroll
    for (int st = 0; st < 4; st++) {
        sA[2 * st]     = NTLOAD(sb + st * 32);
        sA[2 * st + 1] = NTLOAD(sb + st * 32 + 4);
    }
    *(f16x8*)(ftile[0] + fdo)           = gA0;
    *(f16x8*)(ftile[0] + fdo + 32 * CH) = gA1;
    __syncthreads();

    for (int ch = 0; ch < NCH; ch += 2) {
        {
            const f16*   fs = fsrc + (ch + 1) * CH;
            const float* sp = sb + (ch + 1) * CH;
            gB0 = *(const f16x8*)fs;
            gB1 = *(const f16x8*)(fs + (size_t)32 * HW);
            #pragma unroll
            for (int st = 0; st < 4; st++) {
                sB[2 * st]     = NTLOAD(sp + st * 32);
                sB[2 * st + 1] = NTLOAD(sp + st * 32 + 4);
            }
        }
        chunk_compute(sA, ftile[0], c, q, c7, acc, ps);
        *(f16x8*)(ftile[1] + fdo)           = gB0;
        *(f16x8*)(ftile[1] + fdo + 32 * CH) = gB1;
        __syncthreads();

        if (ch + 2 < NCH) {
            const f16*   fs = fsrc + (ch + 2) * CH;
            const float* sp = sb + (ch + 2) * CH;
            gA0 = *(const f16x8*)fs;
            gA1 = *(const f16x8*)(fs + (size_t)32 * HW);
            #pragma unroll
            for (int st = 0; st < 4; st++) {
                sA[2 * st]     = NTLOAD(sp + st * 32);
                sA[2 * st + 1] = NTLOAD(sp + st * 32 + 4);
            }
        }
        chunk_compute(sB, ftile[1], c, q, c7, acc, ps);
        if (ch + 2 < NCH) {
            *(f16x8*)(ftile[0] + fdo)           = gA0;
            *(f16x8*)(ftile[0] + fdo + 32 * CH) = gA1;
            __syncthreads();
        }
    }

    ps += __shfl_xor(ps, 16, 64);
    ps += __shfl_xor(ps, 32, 64);
    if (q == 0)
        S[(size_t)(ms * 4 + bb) * HW + nr + c] = ps;

    #pragma unroll
    for (int u = 0; u < 4; u++)
        *(f32x4*)(P + ((size_t)(ms * 4 + bb) * ND + u * 16 + c) * HW
                  + nr + q * 4) = acc[u];
}

// ---------------------------------------------------------------- kernel C --
__global__ __launch_bounds__(256) void gp_combine(
    const float* __restrict__ P, const float* __restrict__ S,
    float* __restrict__ out)
{
    int g  = blockIdx.x * 256 + threadIdx.x;   // 0 .. 262143
    int n4 = (g & 1023) << 2;
    int bd = g >> 10;                          // b*64 + d, 0..255
    int b  = bd >> 6;
    int d  = bd & 63;

    f32x4 a = (f32x4){0.f, 0.f, 0.f, 0.f};
    f32x4 s = (f32x4){0.f, 0.f, 0.f, 0.f};
    #pragma unroll
    for (int m = 0; m < MS; m++) {
        a += *(const f32x4*)(P + ((size_t)(m * 4 + b) * ND + d) * HW + n4);
        s += *(const f32x4*)(S + (size_t)(m * 4 + b) * HW + n4);
    }
    f32x4 o;
    o[0] = a[0] / s[0]; o[1] = a[1] / s[1];
    o[2] = a[2] / s[2]; o[3] = a[3] / s[3];
    *(f32x4*)(out + (size_t)bd * HW + n4) = o;
}

// ---------------------------------------------------------------- probe -----
// Replays gp_part's EXACT sim address stream (same grid/wave/lane mapping,
// same NT dwordx4 pairs), nothing else: load + accumulate + one dead store.
// Launched 3x after the real chain; (dur - 387.5)/3 = pure pattern-read time.
__global__ __launch_bounds__(512) void sim_probe(
    const float* __restrict__ sim, float* __restrict__ dump)
{
    const int bb   = blockIdx.x >> 7;
    const int ms   = (blockIdx.x >> 5) & 3;
    const int ng   = blockIdx.x & 31;
    const int tid  = threadIdx.x;
    const int wv   = tid >> 6;
    const int lane = tid & 63;
    const int c    = lane & 15;
    const int q    = lane >> 4;
    const int nr   = ng * 128 + wv * 16;

    const float* sb = sim + (size_t)bb * HW * HW + (size_t)(nr + c) * HW
                          + ms * MSL + q * 8;
    f32x4 acc = (f32x4){0.f, 0.f, 0.f, 0.f};
    for (int m0 = 0; m0 < MSL; m0 += 32) {
        acc += NTLOAD(sb + m0);
        acc += NTLOAD(sb + m0 + 4);
    }
    *(f32x4*)(dump + (size_t)blockIdx.x * 2048 + tid * 4) = acc;
}

extern "C" void kernel_launch(void* const* d_in, const int* in_sizes, int n_in,
                              void* d_out, int out_size, void* d_ws, size_t ws_size,
                              hipStream_t stream) {
    (void)in_sizes; (void)n_in; (void)out_size; (void)ws_size;
    const float* sim = (const float*)d_in[0];   // [4, 4096, 4096] fp32
    const float* cw  = (const float*)d_in[1];   // [64, 2] fp32
    const float* cb  = (const float*)d_in[2];   // [64] fp32
    float* out = (float*)d_out;                 // [4, 64, 64, 64] fp32

    // workspace: ft 512 KB @0 ; S 256 KB @512K ; P 16 MB @1M ; probe dump @32M
    f16*   ft   = (f16*)d_ws;
    float* S    = (float*)((char*)d_ws + (512 << 10));
    float* P    = (float*)((char*)d_ws + (1 << 20));
    float* dump = (float*)((char*)d_ws + (32u << 20));

    posenc_f16<<<(ND * HW) / 256, 256, 0, stream>>>(cw, cb, ft);
    gp_part<<<512, 512, 0, stream>>>(sim, ft, P, S);
    gp_combine<<<1024, 256, 0, stream>>>(P, S, out);

    // --- measurement probes (outputs dead; removed next round) ---
    sim_probe<<<512, 512, 0, stream>>>(sim, dump);
    sim_probe<<<512, 512, 0, stream>>>(sim, dump);
    sim_probe<<<512, 512, 0, stream>>>(sim, dump);
}

// Round 5
// 514.802 us; speedup vs baseline: 1.0729x; 1.0729x over previous
//
#include <hip/hip_runtime.h>

// GP_36206574305645: out[b,d,n] = sum_m softmax_m(sim[b,n,m]) * f[m,d]
//   b=4, hw=4096, d=64. sim fp32 268 MB read-once.
// Overhead/iter: ws-poison fill ~160us + input restore ~85us  (~245us).
// R7 probe: gp_part's exact sim stream = 54.9us = 4.9 TB/s -> pattern OK.
//   Traffic at 4.9 TB/s explains R3 (402MB) and R4 (528MB) exactly; R6
//   (~300MB -> 62us floor) measured ~142us chain => ~80us execution loss
//   unique to R6: (a) spills under launch_bounds(512,4) 128-VGPR cap,
//   (b) per-chunk __syncthreads whose vmcnt(0) drain kills the register
//   prefetch pipeline (the structural barrier stall), (c) LDS A-read
//   conflicts. R8 removes all three:
//   - sim staged WAVE-PRIVATE via global_load_lds(16B) into a 4-chunk ring,
//     fragment-ordered (LDS dest = base + lane*16) -> no main-loop barriers,
//     counted s_waitcnt vmcnt(6) keeps 3 chunks in flight (T4).
//   - ft staged ONCE per block, fragment-ordered (64 KB), one barrier total.
//   - all ds_reads are lane-linear -> 0 bank conflicts by construction.
//   - no reg prefetch arrays -> ~70 VGPR, no spills. LDS 128 KB, 1 blk/CU.
//   MS=8 slices, grid 1024 = 4b x 8ms x 32ng; P 32MB + S 512KB partials.
// MEASUREMENT: gp_part launched 3x (idempotent). dur = 245 + 2 + 3G + 8.
//   Pre-committed: dur 420-450 => G~55-65 confirmed, strip next round;
//   dur 550+ => G~100, ablate exp pipe next.

typedef _Float16 f16;
typedef f16 f16x8 __attribute__((ext_vector_type(8)));
typedef float f32x4 __attribute__((ext_vector_type(4)));

static constexpr int HW  = 4096;
static constexpr int ND  = 64;
static constexpr int MS  = 8;        // m-slices (softmax split)
static constexpr int MSL = HW / MS;  // 512 m per slice
static constexpr int NCH = MSL / 32; // 16 chunks of 32 m

#define GLD16(gp, lp) __builtin_amdgcn_global_load_lds(                        \
    (const __attribute__((address_space(1))) void*)(gp),                       \
    (__attribute__((address_space(3))) void*)(lp), 16, 0, 0)

// ---------------------------------------------------------------- kernel A --
__global__ __launch_bounds__(256) void posenc_f16(
    const float* __restrict__ cw, const float* __restrict__ cb,
    f16* __restrict__ ft)
{
    int g = blockIdx.x * 256 + threadIdx.x;      // 0 .. 64*4096-1
    int d = g >> 12;
    int m = g & 4095;
    int i = m >> 6;
    int j = m & 63;
    float gx = (float)(2 * j - 63) * (1.0f / 64.0f);
    float gy = (float)(2 * i - 63) * (1.0f / 64.0f);
    float proj = cw[2 * d] * gx + cw[2 * d + 1] * gy + cb[d];
    float v = cosf(25.132741228718345f * proj);  // 8*pi
    ft[(size_t)d * HW + m] = (f16)v;
}

// ---------------------------------------------------------------- kernel B --
// 8 waves x 16 n-rows = 128 rows/block; one 512-m slice per block.
// Fragment-ordered LDS (written via per-lane global src, linear LDS dest):
//   ftl[(st*4+u)*512 + lane*8]  <- ft row u*16+(lane&15), k=st*32+(lane>>4)*8
//   simw[wv][(ch&3)*512 + h*256 + lane*4] <- sim row nr+(lane&15),
//                                            m=ch*32+(lane>>4)*8+h*4
// A-frag (lane c,q): k=q*8+j ; B-frag: row u*16+c, k=q*8+j ; C/D: col=c,
// row(n)=q*4+reg (verified layout, passing since R3).
__global__ __launch_bounds__(512) void gp_part(
    const float* __restrict__ sim, const f16* __restrict__ ft,
    float* __restrict__ P, float* __restrict__ S)
{
    const int bb   = blockIdx.x >> 8;          // batch
    const int ms   = (blockIdx.x >> 5) & 7;    // m-slice
    const int ng   = blockIdx.x & 31;          // 128-row n-group
    const int tid  = threadIdx.x;
    const int wv   = tid >> 6;
    const int lane = tid & 63;
    const int c    = lane & 15;
    const int q    = lane >> 4;

    __shared__ f16   ftl[64 * 512];            // 64 KB, frag-ordered
    __shared__ float simw[8][4 * 512];         // 64 KB, per-wave 4-chunk ring

    const int mb = ms * MSL;
    const int nr = ng * 128 + wv * 16;

    // per-lane global sources (LDS side of GLD16 is wave-uniform + lane*16)
    const float* ssrc = sim + (size_t)bb * HW * HW + (size_t)(nr + c) * HW
                            + mb + q * 8;

    f32x4 acc[4];
    #pragma unroll
    for (int u = 0; u < 4; u++)
        acc[u] = (f32x4){0.f, 0.f, 0.f, 0.f};
    float ps = 0.f;

    auto stage_sim = [&](int ch) {
        const float* g = ssrc + ch * 32;
        float* l = &simw[wv][(ch & 3) * 512];
        GLD16(g,     l);          // h=0: floats q*8+0..3 of 16 rows
        GLD16(g + 4, l + 256);    // h=1: floats q*8+4..7
    };

    // ---- prologue: ft (once, 8 instr/wave) + sim chunks 0..3; one barrier
    #pragma unroll
    for (int r = 0; r < 8; ++r) {
        int p  = r * 8 + wv;
        int st = p >> 2, u = p & 3;
        GLD16(ft + (size_t)(u * 16 + c) * HW + mb + st * 32 + q * 8,
              &ftl[(st * 4 + u) * 512]);
    }
    #pragma unroll
    for (int ch = 0; ch < 4; ++ch)
        stage_sim(ch);
    __syncthreads();              // drains vmcnt(0): ft + chunks 0..3 resident

    auto body = [&](int ch) {
        const float* lw = &simw[wv][(ch & 3) * 512];
        f32x4 s0 = *(const f32x4*)(lw + lane * 4);
        f32x4 s1 = *(const f32x4*)(lw + 256 + lane * 4);
        float p0 = __expf(s0[0]); float p1 = __expf(s0[1]);
        float p2 = __expf(s0[2]); float p3 = __expf(s0[3]);
        float p4 = __expf(s1[0]); float p5 = __expf(s1[1]);
        float p6 = __expf(s1[2]); float p7 = __expf(s1[3]);
        ps += ((p0 + p1) + (p2 + p3)) + ((p4 + p5) + (p6 + p7));
        f16x8 a;
        a[0] = (f16)p0; a[1] = (f16)p1; a[2] = (f16)p2; a[3] = (f16)p3;
        a[4] = (f16)p4; a[5] = (f16)p5; a[6] = (f16)p6; a[7] = (f16)p7;
        const f16* fb = &ftl[ch * 2048 + lane * 8];
        f16x8 b0 = *(const f16x8*)(fb);
        f16x8 b1 = *(const f16x8*)(fb + 512);
        f16x8 b2 = *(const f16x8*)(fb + 1024);
        f16x8 b3 = *(const f16x8*)(fb + 1536);
        acc[0] = __builtin_amdgcn_mfma_f32_16x16x32_f16(a, b0, acc[0], 0, 0, 0);
        acc[1] = __builtin_amdgcn_mfma_f32_16x16x32_f16(a, b1, acc[1], 0, 0, 0);
        acc[2] = __builtin_amdgcn_mfma_f32_16x16x32_f16(a, b2, acc[2], 0, 0, 0);
        acc[3] = __builtin_amdgcn_mfma_f32_16x16x32_f16(a, b3, acc[3], 0, 0, 0);
    };

    // ---- main loop: no barriers; steady state 8 loads (4 chunks) in flight.
    // vmcnt(6) => current chunk's 2 loads done. lgkmcnt(0) before re-staging
    // the ring slot guarantees our ds_reads of that slot retired (WAR).
    for (int ch = 0; ch < 13; ++ch) {
        asm volatile("s_waitcnt vmcnt(6)" ::: "memory");
        body(ch);
        if (ch < 12) {
            asm volatile("s_waitcnt lgkmcnt(0)" ::: "memory");
            stage_sim(ch + 4);
        }
    }
    asm volatile("s_waitcnt vmcnt(4)" ::: "memory"); body(13);
    asm volatile("s_waitcnt vmcnt(2)" ::: "memory"); body(14);
    asm volatile("s_waitcnt vmcnt(0)" ::: "memory"); body(15);

    // ---- epilogue: slice row-sums + unnormalized partials ----
    ps += __shfl_xor(ps, 16, 64);
    ps += __shfl_xor(ps, 32, 64);                 // full row-c sum over slice
    if (q == 0)
        S[(size_t)(ms * 4 + bb) * HW + nr + c] = ps;

    #pragma unroll
    for (int u = 0; u < 4; u++)
        *(f32x4*)(P + ((size_t)(ms * 4 + bb) * ND + u * 16 + c) * HW
                  + nr + q * 4) = acc[u];
}

// ---------------------------------------------------------------- kernel C --
// out[b][d][n] = sum_ms P[ms][b][d][n] / sum_ms S[ms][b][n]
// 1,048,576 outputs / 4 per thread = 1024 blocks x 256 threads.
__global__ __launch_bounds__(256) void gp_combine(
    const float* __restrict__ P, const float* __restrict__ S,
    float* __restrict__ out)
{
    int g  = blockIdx.x * 256 + threadIdx.x;   // 0 .. 262143
    int n4 = (g & 1023) << 2;
    int bd = g >> 10;                          // b*64 + d, 0..255
    int b  = bd >> 6;
    int d  = bd & 63;

    f32x4 a = (f32x4){0.f, 0.f, 0.f, 0.f};
    f32x4 s = (f32x4){0.f, 0.f, 0.f, 0.f};
    #pragma unroll
    for (int m = 0; m < MS; m++) {
        a += *(const f32x4*)(P + ((size_t)(m * 4 + b) * ND + d) * HW + n4);
        s += *(const f32x4*)(S + (size_t)(m * 4 + b) * HW + n4);
    }
    f32x4 o;
    o[0] = a[0] / s[0]; o[1] = a[1] / s[1];
    o[2] = a[2] / s[2]; o[3] = a[3] / s[3];
    *(f32x4*)(out + (size_t)bd * HW + n4) = o;
}

extern "C" void kernel_launch(void* const* d_in, const int* in_sizes, int n_in,
                              void* d_out, int out_size, void* d_ws, size_t ws_size,
                              hipStream_t stream) {
    (void)in_sizes; (void)n_in; (void)out_size; (void)ws_size;
    const float* sim = (const float*)d_in[0];   // [4, 4096, 4096] fp32
    const float* cw  = (const float*)d_in[1];   // [64, 2] fp32
    const float* cb  = (const float*)d_in[2];   // [64] fp32
    float* out = (float*)d_out;                 // [4, 64, 64, 64] fp32

    // workspace: ft 512 KB @0 ; S 512 KB @512K ; P 32 MB @1M
    f16*   ft = (f16*)d_ws;
    float* S  = (float*)((char*)d_ws + (512 << 10));
    float* P  = (float*)((char*)d_ws + (1 << 20));

    posenc_f16<<<(ND * HW) / 256, 256, 0, stream>>>(cw, cb, ft);
    // 3x launch (idempotent): dur_us decomposition gives exact gp_part time.
    gp_part<<<1024, 512, 0, stream>>>(sim, ft, P, S);
    gp_part<<<1024, 512, 0, stream>>>(sim, ft, P, S);
    gp_part<<<1024, 512, 0, stream>>>(sim, ft, P, S);
    gp_combine<<<1024, 256, 0, stream>>>(P, S, out);
}

// Round 6
// 374.877 us; speedup vs baseline: 1.4734x; 1.3733x over previous
//
#include <hip/hip_runtime.h>

// GP_36206574305645: out[b,d,n] = sum_m softmax_m(sim[b,n,m]) * f[m,d]
//   b=4, hw=4096, d=64. sim fp32 268 MB read-once.
// Overhead/iter: ws-poison fill ~160us + input restore ~85us  (~245us).
// R7 probe: gp_part's exact sim stream = 54.9us = 4.9 TB/s (pattern OK).
// R8 (3x-launch measurement): G(gp_part) = (514.8-255)/3 ~ 86.6us.
//   Barrier-free wave-private ring fixed R6's ~45us execution loss.
//   Remaining budget at 4.9 TB/s: sim 55 + P/S 7 + ft-rereads ~13 (64 KB/blk
//   x 1024 blks; sim stream evicts ft's 512 KB from L2) + prologue/tail ~8
//   = ~83 ~= measured 87. Model closes.
// R9: (a) single gp_part launch (-2G = -173us); (b) sim staged with NT
//   cache policy (aux=2 on global_load_lds): stream-once data stops
//   thrashing L2 -> ft stays resident, its re-reads become L2 hits.
//   Predict total ~330-342us.
// Structure (unchanged from R8, passing): 8 waves x 16 n-rows = 128
//   rows/block, one 512-m slice; ftl staged once frag-ordered (64 KB, one
//   barrier); sim wave-private 4-chunk LDS ring via global_load_lds(16B),
//   counted vmcnt(6), zero main-loop barriers; lane-linear ds_reads (0
//   conflicts); MS=8 softmax split -> P/S partials + combine kernel.
//   Single-pass softmax, no max-subtraction (sim~N(0,1), exp<=~500, f16-safe).

typedef _Float16 f16;
typedef f16 f16x8 __attribute__((ext_vector_type(8)));
typedef float f32x4 __attribute__((ext_vector_type(4)));

static constexpr int HW  = 4096;
static constexpr int ND  = 64;
static constexpr int MS  = 8;        // m-slices (softmax split)
static constexpr int MSL = HW / MS;  // 512 m per slice

// normal cache policy (ft: keep in L2)
#define GLD16(gp, lp) __builtin_amdgcn_global_load_lds(                        \
    (const __attribute__((address_space(1))) void*)(gp),                       \
    (__attribute__((address_space(3))) void*)(lp), 16, 0, 0)
// non-temporal (sim: stream-once, don't pollute L2)
#define GLD16NT(gp, lp) __builtin_amdgcn_global_load_lds(                      \
    (const __attribute__((address_space(1))) void*)(gp),                       \
    (__attribute__((address_space(3))) void*)(lp), 16, 0, 2)

// ---------------------------------------------------------------- kernel A --
__global__ __launch_bounds__(256) void posenc_f16(
    const float* __restrict__ cw, const float* __restrict__ cb,
    f16* __restrict__ ft)
{
    int g = blockIdx.x * 256 + threadIdx.x;      // 0 .. 64*4096-1
    int d = g >> 12;
    int m = g & 4095;
    int i = m >> 6;
    int j = m & 63;
    float gx = (float)(2 * j - 63) * (1.0f / 64.0f);
    float gy = (float)(2 * i - 63) * (1.0f / 64.0f);
    float proj = cw[2 * d] * gx + cw[2 * d + 1] * gy + cb[d];
    float v = cosf(25.132741228718345f * proj);  // 8*pi
    ft[(size_t)d * HW + m] = (f16)v;
}

// ---------------------------------------------------------------- kernel B --
// Fragment-ordered LDS (per-lane global src, linear LDS dest):
//   ftl[(st*4+u)*512 + lane*8]  <- ft row u*16+(lane&15), k=st*32+(lane>>4)*8
//   simw[wv][(ch&3)*512 + h*256 + lane*4] <- sim row nr+(lane&15),
//                                            m=ch*32+(lane>>4)*8+h*4
// A-frag (lane c,q): k=q*8+j ; B-frag: row u*16+c, k=q*8+j ; C/D: col=c,
// row(n)=q*4+reg (verified layout, passing since R3).
__global__ __launch_bounds__(512) void gp_part(
    const float* __restrict__ sim, const f16* __restrict__ ft,
    float* __restrict__ P, float* __restrict__ S)
{
    const int bb   = blockIdx.x >> 8;          // batch
    const int ms   = (blockIdx.x >> 5) & 7;    // m-slice
    const int ng   = blockIdx.x & 31;          // 128-row n-group
    const int tid  = threadIdx.x;
    const int wv   = tid >> 6;
    const int lane = tid & 63;
    const int c    = lane & 15;
    const int q    = lane >> 4;

    __shared__ f16   ftl[64 * 512];            // 64 KB, frag-ordered
    __shared__ float simw[8][4 * 512];         // 64 KB, per-wave 4-chunk ring

    const int mb = ms * MSL;
    const int nr = ng * 128 + wv * 16;

    const float* ssrc = sim + (size_t)bb * HW * HW + (size_t)(nr + c) * HW
                            + mb + q * 8;

    f32x4 acc[4];
    #pragma unroll
    for (int u = 0; u < 4; u++)
        acc[u] = (f32x4){0.f, 0.f, 0.f, 0.f};
    float ps = 0.f;

    auto stage_sim = [&](int ch) {
        const float* g = ssrc + ch * 32;
        float* l = &simw[wv][(ch & 3) * 512];
        GLD16NT(g,     l);        // h=0: floats q*8+0..3 of 16 rows
        GLD16NT(g + 4, l + 256);  // h=1: floats q*8+4..7
    };

    // ---- prologue: ft (once, 8 instr/wave) + sim chunks 0..3; one barrier
    #pragma unroll
    for (int r = 0; r < 8; ++r) {
        int p  = r * 8 + wv;
        int st = p >> 2, u = p & 3;
        GLD16(ft + (size_t)(u * 16 + c) * HW + mb + st * 32 + q * 8,
              &ftl[(st * 4 + u) * 512]);
    }
    #pragma unroll
    for (int ch = 0; ch < 4; ++ch)
        stage_sim(ch);
    __syncthreads();              // drains vmcnt(0): ft + chunks 0..3 resident

    auto body = [&](int ch) {
        const float* lw = &simw[wv][(ch & 3) * 512];
        f32x4 s0 = *(const f32x4*)(lw + lane * 4);
        f32x4 s1 = *(const f32x4*)(lw + 256 + lane * 4);
        float p0 = __expf(s0[0]); float p1 = __expf(s0[1]);
        float p2 = __expf(s0[2]); float p3 = __expf(s0[3]);
        float p4 = __expf(s1[0]); float p5 = __expf(s1[1]);
        float p6 = __expf(s1[2]); float p7 = __expf(s1[3]);
        ps += ((p0 + p1) + (p2 + p3)) + ((p4 + p5) + (p6 + p7));
        f16x8 a;
        a[0] = (f16)p0; a[1] = (f16)p1; a[2] = (f16)p2; a[3] = (f16)p3;
        a[4] = (f16)p4; a[5] = (f16)p5; a[6] = (f16)p6; a[7] = (f16)p7;
        const f16* fb = &ftl[ch * 2048 + lane * 8];
        f16x8 b0 = *(const f16x8*)(fb);
        f16x8 b1 = *(const f16x8*)(fb + 512);
        f16x8 b2 = *(const f16x8*)(fb + 1024);
        f16x8 b3 = *(const f16x8*)(fb + 1536);
        acc[0] = __builtin_amdgcn_mfma_f32_16x16x32_f16(a, b0, acc[0], 0, 0, 0);
        acc[1] = __builtin_amdgcn_mfma_f32_16x16x32_f16(a, b1, acc[1], 0, 0, 0);
        acc[2] = __builtin_amdgcn_mfma_f32_16x16x32_f16(a, b2, acc[2], 0, 0, 0);
        acc[3] = __builtin_amdgcn_mfma_f32_16x16x32_f16(a, b3, acc[3], 0, 0, 0);
    };

    // ---- main loop: no barriers; steady state 8 loads (4 chunks) in flight.
    // vmcnt(6) => current chunk's 2 loads done. lgkmcnt(0) before re-staging
    // the ring slot guarantees our ds_reads of that slot retired (WAR).
    for (int ch = 0; ch < 13; ++ch) {
        asm volatile("s_waitcnt vmcnt(6)" ::: "memory");
        body(ch);
        if (ch < 12) {
            asm volatile("s_waitcnt lgkmcnt(0)" ::: "memory");
            stage_sim(ch + 4);
        }
    }
    asm volatile("s_waitcnt vmcnt(4)" ::: "memory"); body(13);
    asm volatile("s_waitcnt vmcnt(2)" ::: "memory"); body(14);
    asm volatile("s_waitcnt vmcnt(0)" ::: "memory"); body(15);

    // ---- epilogue: slice row-sums + unnormalized partials ----
    ps += __shfl_xor(ps, 16, 64);
    ps += __shfl_xor(ps, 32, 64);                 // full row-c sum over slice
    if (q == 0)
        S[(size_t)(ms * 4 + bb) * HW + nr + c] = ps;

    #pragma unroll
    for (int u = 0; u < 4; u++)
        *(f32x4*)(P + ((size_t)(ms * 4 + bb) * ND + u * 16 + c) * HW
                  + nr + q * 4) = acc[u];
}

// ---------------------------------------------------------------- kernel C --
// out[b][d][n] = sum_ms P[ms][b][d][n] / sum_ms S[ms][b][n]
// 1,048,576 outputs / 4 per thread = 1024 blocks x 256 threads.
__global__ __launch_bounds__(256) void gp_combine(
    const float* __restrict__ P, const float* __restrict__ S,
    float* __restrict__ out)
{
    int g  = blockIdx.x * 256 + threadIdx.x;   // 0 .. 262143
    int n4 = (g & 1023) << 2;
    int bd = g >> 10;                          // b*64 + d, 0..255
    int b  = bd >> 6;
    int d  = bd & 63;

    f32x4 a = (f32x4){0.f, 0.f, 0.f, 0.f};
    f32x4 s = (f32x4){0.f, 0.f, 0.f, 0.f};
    #pragma unroll
    for (int m = 0; m < MS; m++) {
        a += *(const f32x4*)(P + ((size_t)(m * 4 + b) * ND + d) * HW + n4);
        s += *(const f32x4*)(S + (size_t)(m * 4 + b) * HW + n4);
    }
    f32x4 o;
    o[0] = a[0] / s[0]; o[1] = a[1] / s[1];
    o[2] = a[2] / s[2]; o[3] = a[3] / s[3];
    *(f32x4*)(out + (size_t)bd * HW + n4) = o;
}

extern "C" void kernel_launch(void* const* d_in, const int* in_sizes, int n_in,
                              void* d_out, int out_size, void* d_ws, size_t ws_size,
                              hipStream_t stream) {
    (void)in_sizes; (void)n_in; (void)out_size; (void)ws_size;
    const float* sim = (const float*)d_in[0];   // [4, 4096, 4096] fp32
    const float* cw  = (const float*)d_in[1];   // [64, 2] fp32
    const float* cb  = (const float*)d_in[2];   // [64] fp32
    float* out = (float*)d_out;                 // [4, 64, 64, 64] fp32

    // workspace: ft 512 KB @0 ; S 512 KB @512K ; P 32 MB @1M
    f16*   ft = (f16*)d_ws;
    float* S  = (float*)((char*)d_ws + (512 << 10));
    float* P  = (float*)((char*)d_ws + (1 << 20));

    posenc_f16<<<(ND * HW) / 256, 256, 0, stream>>>(cw, cb, ft);
    gp_part<<<1024, 512, 0, stream>>>(sim, ft, P, S);
    gp_combine<<<1024, 256, 0, stream>>>(P, S, out);
}